// Round 5
// baseline (33909.818 us; speedup 1.0000x reference)
//
#include <hip/hip_runtime.h>
#include <math.h>

// FISTA compressed-sensing iteration, one workgroup per batch element.
//
// Phase decomposition: ih = 8*qh + ph (72 = 8*9 exactly). The 40x40 stride-8
// SAME conv A becomes sum over 64 phases of 5x5 convs on 9x9 grids:
//   a[oh,ow,co] = sum_{p,th,tw,ci} ys[p][oh+th-2][ow+tw-2][ci] * W_A[p][th][tw][ci][co]
// with W_A[...] = w_conv[8*th+ph][8*tw+pw][ci][co]  (SAME pad lo=16).
// conv_transpose (k=5,s=8,'SAME' => jax pads (4,7)): out[8q+rh] (rh<=4) reads
// only r[q] with weight w_ct[4-rh][4-rw] -> elementwise stage.
//
// R5 evidence trail:
//  - R2 (648,3) AND R4 (648 plain) both got VGPR_Count=84 + 41 GB HBM scratch
//    traffic. Revised model: the backend sets the VGPR budget from the max
//    occupancy achievable given LDS (64 KiB/WG -> 2 WG/CU -> 22 waves -> 6
//    waves/EU -> 512/6 = 84) and SPILLS to reach it. launch_bounds' second
//    arg is only a lower bound on occupancy -- it can't stop this.
//  - Fix: amdgpu_waves_per_eu(1, 3) caps the occupancy target at 3 waves/EU
//    -> VGPR budget 512/3 ~= 170 >= ~150-reg live set -> no spills. The lost
//    2nd WG/CU is irrelevant: 64 WGs on 256 CUs.
//  - y_last in 24 VGPRs/thread; d_out written once (final iter). Weights from
//    global (57.6 KB, L2-resident). Static 65,484 B LDS (R3's >64KB dynamic
//    LDS aborted at launch).

#define ITERS 200
#define SLAB 252          // floats per phase slab (9 rows * 28)
#define ROWSTRIDE 28      // 27 used + 1 zero pad, rows 16B aligned
#define YS_FLOATS (64 * SLAB)          // 16128
#define A_OFF YS_FLOATS                // a-array: 243 floats (9x9x3)
#define SMEM_FLOATS (YS_FLOATS + 243)  // 16371 floats = 65,484 B <= 64 KiB

template <int CTRL>
__device__ __forceinline__ float dpp_add(float x) {
  int moved = __builtin_amdgcn_update_dpp(0, __float_as_int(x), CTRL, 0xF, 0xF, true);
  return x + __int_as_float(moved);
}
// Classic gfx9 wave64 sum; result valid in lane 63. All VALU (no LDS pipe).
__device__ __forceinline__ float wave_sum64_to_lane63(float x) {
  x = dpp_add<0x111>(x);  // row_shr:1
  x = dpp_add<0x112>(x);  // row_shr:2
  x = dpp_add<0x114>(x);  // row_shr:4
  x = dpp_add<0x118>(x);  // row_shr:8
  x = dpp_add<0x142>(x);  // row_bcast15
  x = dpp_add<0x143>(x);  // row_bcast31
  return x;
}

// Reorder weights once per call (d_ws is re-poisoned before every timed call).
// W_A[((th*5+tw)*3+ci)*192 + p*3 + co] = w_conv[8*th+ph][8*tw+pw][ci][co]
// Wct[((rh*8+rw)*3+c)*3 + ci] = (rh<5 && rw<5) ? w_ct[4-rh][4-rw][ci][c] : 0
__global__ void init_w_kernel(const float* __restrict__ w_conv,
                              const float* __restrict__ w_ct,
                              float* __restrict__ W_A,
                              float* __restrict__ Wct) {
  int i = blockIdx.x * blockDim.x + threadIdx.x;
  if (i < 14400) {
    int co = i % 3;
    int rest = i / 3;
    int p = rest % 64;
    int j = rest / 64;
    int ci = j % 3;
    int tt = j / 3;
    int tw = tt % 5;
    int th = tt / 5;
    int pw = p % 8;
    int ph = p / 8;
    int kh = 8 * th + ph;
    int kw = 8 * tw + pw;
    W_A[i] = w_conv[((kh * 40 + kw) * 3 + ci) * 3 + co];
  }
  if (i < 576) {
    int ci = i % 3;
    int r1 = i / 3;
    int c = r1 % 3;
    int r2 = r1 / 3;
    int rw = r2 % 8;
    int rh = r2 / 8;
    float v = 0.f;
    if (rh < 5 && rw < 5) v = w_ct[(((4 - rh) * 5 + (4 - rw)) * 3 + ci) * 3 + c];
    Wct[i] = v;
  }
}

__global__ __launch_bounds__(648)
__attribute__((amdgpu_waves_per_eu(1, 3)))
void fista_kernel(
    const float* __restrict__ x, const float* __restrict__ lam,
    const float* __restrict__ b_conv, const float* __restrict__ b_ct,
    const float* __restrict__ W_A, const float* __restrict__ Wct,
    float* __restrict__ out) {
  __shared__ __align__(16) float smem[SMEM_FLOATS];
  const int tid = threadIdx.x;
  const int n = blockIdx.x;
  const int lane = tid & 63;
  const int widx = tid >> 6;

  // zero y_tmp + a (pads included: col-27 pad must stay 0 for bw==2 over-read)
  for (int i = tid; i < SMEM_FLOATS; i += 648) smem[i] = 0.f;

  // ---- stage-2 (At + elementwise) identity: thread = (part=rh, cell=(qh,qw))
  const int part = tid / 81;  // rh in [0,8)
  const int cell = tid % 81;  // qh*9+qw
  const int qh = cell / 9;
  const int qw = cell % 9;
  const float lam_n = lam[n];
  const float x0 = x[n * 243 + cell * 3 + 0];
  const float x1 = x[n * 243 + cell * 3 + 1];
  const float x2 = x[n * 243 + cell * 3 + 2];
  const float bct0 = b_ct[0], bct1 = b_ct[1], bct2 = b_ct[2];
  const int ys2_base = part * 2016 + qh * ROWSTRIDE + qw * 3;  // + rw*SLAB + c
  const bool part_live = (part < 5);

  // y_last in registers: same thread owns the same 24 elements all 200 iters.
  // beta_0 = 0 so the init value is never used meaningfully.
  float ylr[24];
#pragma unroll
  for (int j = 0; j < 24; ++j) ylr[j] = 0.f;

  // ---- stage-1 (A) identity: wave = 3x3 output block, lane = phase
  const int bh = widx / 3;
  const int bw = widx - bh * 3;  // only meaningful for widx<9
  const float bcv0 = b_conv[0], bcv1 = b_conv[1], bcv2 = b_conv[2];
  const int ys1_base = lane * SLAB;
  const float* __restrict__ WAp = W_A + lane * 3;

  __syncthreads();

  float t = 1.0f;
#pragma unroll 1
  for (int iter = 0; iter < ITERS; ++iter) {
    // ================= stage 1: a = A(y_tmp) + b_conv, waves 0..8 =================
    if (widx < 9) {
      float acc[27];
#pragma unroll
      for (int k = 0; k < 27; ++k) acc[k] = 0.f;
      float yreg[3][21];  // sliding 3-row window, 7 cols x 3 ci

      auto load_row = [&](float* yr, int q) {
        if ((unsigned)q > 8u) {
#pragma unroll
          for (int k = 0; k < 21; ++k) yr[k] = 0.f;
          return;
        }
        const float* bp = &smem[ys1_base + q * ROWSTRIDE];
        if (bw == 0) {  // LDS cols 0..14 -> regs 6..20 ; regs 0..5 = qw {-2,-1} = 0
          float4 f0 = *(const float4*)(bp + 0);
          float4 f1 = *(const float4*)(bp + 4);
          float4 f2 = *(const float4*)(bp + 8);
          float4 f3 = *(const float4*)(bp + 12);
          yr[0]=0.f; yr[1]=0.f; yr[2]=0.f; yr[3]=0.f; yr[4]=0.f; yr[5]=0.f;
          yr[6]=f0.x; yr[7]=f0.y; yr[8]=f0.z; yr[9]=f0.w;
          yr[10]=f1.x; yr[11]=f1.y; yr[12]=f1.z; yr[13]=f1.w;
          yr[14]=f2.x; yr[15]=f2.y; yr[16]=f2.z; yr[17]=f2.w;
          yr[18]=f3.x; yr[19]=f3.y; yr[20]=f3.z;
        } else if (bw == 1) {  // LDS cols 3..23 -> regs 0..20
          float4 f0 = *(const float4*)(bp + 0);
          float4 f1 = *(const float4*)(bp + 4);
          float4 f2 = *(const float4*)(bp + 8);
          float4 f3 = *(const float4*)(bp + 12);
          float4 f4 = *(const float4*)(bp + 16);
          float4 f5 = *(const float4*)(bp + 20);
          yr[0]=f0.w;
          yr[1]=f1.x; yr[2]=f1.y; yr[3]=f1.z; yr[4]=f1.w;
          yr[5]=f2.x; yr[6]=f2.y; yr[7]=f2.z; yr[8]=f2.w;
          yr[9]=f3.x; yr[10]=f3.y; yr[11]=f3.z; yr[12]=f3.w;
          yr[13]=f4.x; yr[14]=f4.y; yr[15]=f4.z; yr[16]=f4.w;
          yr[17]=f5.x; yr[18]=f5.y; yr[19]=f5.z; yr[20]=f5.w;
        } else {  // LDS cols 12..26 -> regs 0..14 ; regs 15..20 = qw {9,10} = 0
          float4 f0 = *(const float4*)(bp + 12);
          float4 f1 = *(const float4*)(bp + 16);
          float4 f2 = *(const float4*)(bp + 20);
          float4 f3 = *(const float4*)(bp + 24);  // .w reads the zero pad (in-bounds)
          yr[0]=f0.x; yr[1]=f0.y; yr[2]=f0.z; yr[3]=f0.w;
          yr[4]=f1.x; yr[5]=f1.y; yr[6]=f1.z; yr[7]=f1.w;
          yr[8]=f2.x; yr[9]=f2.y; yr[10]=f2.z; yr[11]=f2.w;
          yr[12]=f3.x; yr[13]=f3.y; yr[14]=f3.z;
          yr[15]=0.f; yr[16]=0.f; yr[17]=0.f; yr[18]=0.f; yr[19]=0.f; yr[20]=0.f;
        }
      };

      load_row(yreg[1], 3 * bh - 2);
      load_row(yreg[2], 3 * bh - 1);
      load_row(yreg[0], 3 * bh + 0);

#pragma unroll
      for (int th = 0; th < 5; ++th) {
#pragma unroll
        for (int tw = 0; tw < 5; ++tw) {
#pragma unroll
          for (int ci = 0; ci < 3; ++ci) {
            const float* wp = WAp + ((th * 5 + tw) * 3 + ci) * 192;
            const float w0 = wp[0];
            const float w1 = wp[1];
            const float w2 = wp[2];
#pragma unroll
            for (int pr = 0; pr < 3; ++pr) {
              const int slot = (th + 1 + pr) % 3;  // row (3bh+pr+th-2)
#pragma unroll
              for (int pc = 0; pc < 3; ++pc) {
                const float yv = yreg[slot][(pc + tw) * 3 + ci];
                acc[(pr * 3 + pc) * 3 + 0] += yv * w0;
                acc[(pr * 3 + pc) * 3 + 1] += yv * w1;
                acc[(pr * 3 + pc) * 3 + 2] += yv * w2;
              }
            }
          }
        }
        if (th < 4) load_row(yreg[(th + 1) % 3], 3 * bh + th + 1);
      }

#pragma unroll
      for (int k = 0; k < 27; ++k) acc[k] = wave_sum64_to_lane63(acc[k]);
      if (lane == 63) {
        const int abase = A_OFF + 81 * bh + 9 * bw;  // a[qh][qw][co] = 27qh+3qw+co
#pragma unroll
        for (int k = 0; k < 27; ++k) {
          const int pr = k / 9;
          const int pc = (k / 3) % 3;
          const int co = k % 3;
          const float bc = (co == 0) ? bcv0 : ((co == 1) ? bcv1 : bcv2);
          smem[abase + 27 * pr + 3 * pc + co] = acc[k] + bc;
        }
      }
    }
    __syncthreads();

    const float tn = (1.0f + sqrtf(1.0f + 4.0f * t * t)) * 0.5f;
    const float beta = (t - 1.0f) / tn;  // beta_0 = 0
    t = tn;

    // ================= stage 2: r = x - a; re = At(r)+b_ct; ST; momentum ========
    const float a0 = smem[A_OFF + cell * 3 + 0];
    const float a1 = smem[A_OFF + cell * 3 + 1];
    const float a2 = smem[A_OFF + cell * 3 + 2];
    const float r0 = x0 - a0;
    const float r1 = x1 - a1;
    const float r2 = x2 - a2;

    if (iter < ITERS - 1) {
#pragma unroll
      for (int j = 0; j < 24; ++j) {  // j = rw*3 + c
        const int rw = j / 3;
        const int c = j - rw * 3;
        const float bc = (c == 0) ? bct0 : ((c == 1) ? bct1 : bct2);
        float re = bc;
        if (rw < 5 && part_live) {  // other taps are structurally zero
          const float* wp = Wct + ((part * 8 + rw) * 3 + c) * 3;
          re += r0 * wp[0] + r1 * wp[1] + r2 * wp[2];
        }
        const int ya = ys2_base + rw * SLAB + c;
        const float yt = smem[ya];
        const float wv = yt - re;
        const float yn = fmaxf(wv - lam_n, 0.f) - fmaxf(-wv - lam_n, 0.f);
        const float yl = ylr[j];
        ylr[j] = yn;
        smem[ya] = yn + beta * (yn - yl);
      }
    } else {
      // final iteration: y_new IS the output; write standard NHWC layout.
#pragma unroll
      for (int j = 0; j < 24; ++j) {
        const int rw = j / 3;
        const int c = j - rw * 3;
        const float bc = (c == 0) ? bct0 : ((c == 1) ? bct1 : bct2);
        float re = bc;
        if (rw < 5 && part_live) {
          const float* wp = Wct + ((part * 8 + rw) * 3 + c) * 3;
          re += r0 * wp[0] + r1 * wp[1] + r2 * wp[2];
        }
        const int ya = ys2_base + rw * SLAB + c;
        const float yt = smem[ya];
        const float wv = yt - re;
        const float yn = fmaxf(wv - lam_n, 0.f) - fmaxf(-wv - lam_n, 0.f);
        const int ih = 8 * qh + part;
        const int iw = 8 * qw + rw;
        out[((n * 72 + ih) * 72 + iw) * 3 + c] = yn;
      }
    }
    __syncthreads();
  }
}

extern "C" void kernel_launch(void* const* d_in, const int* in_sizes, int n_in,
                              void* d_out, int out_size, void* d_ws, size_t ws_size,
                              hipStream_t stream) {
  const float* x      = (const float*)d_in[0];
  const float* lam    = (const float*)d_in[1];
  const float* w_conv = (const float*)d_in[2];
  const float* b_conv = (const float*)d_in[3];
  const float* w_ct   = (const float*)d_in[4];
  const float* b_ct   = (const float*)d_in[5];
  float* out = (float*)d_out;

  float* W_A = (float*)d_ws;          // 14400 floats
  float* Wct = W_A + 14400;           // 576 floats

  hipLaunchKernelGGL(init_w_kernel, dim3(57), dim3(256), 0, stream,
                     w_conv, w_ct, W_A, Wct);
  hipLaunchKernelGGL(fista_kernel, dim3(64), dim3(648), 0, stream,
                     x, lam, b_conv, b_ct, W_A, Wct, out);
}

// Round 9
// 4708.430 us; speedup vs baseline: 7.2019x; 7.2019x over previous
//
#include <hip/hip_runtime.h>
#include <math.h>

// FISTA compressed-sensing loop as 200 x (conv kernel + elementwise kernel).
//
// R9 rationale: R2/R4/R5 (monolithic, PASS) were 34 ms: 64KiB LDS forced a
// VGPR budget of 84 -> ~41 GB spill traffic, and 64 blocks used 8% of chip.
// R6/R7/R8 restructured the monolith and all failed correctness with no
// semantic diff found; common factor was complex window code under the
// spill-everything regime. This design removes LDS, spills, lambdas, and the
// in-kernel barrier entirely: the launch boundary is the barrier.
//
// Phase decomposition (proven R2-R5): ih = 8*qh + ph. A (40x40 s8 SAME) =
// sum over 64 phases of 5x5 convs on the 9x9 grid. At (k=5 s8 SAME, jax pads
// (4,7)): out[8q+rh] (rh<=4) reads only r[q] with w_ct[4-rh][4-rw] ->
// elementwise; zero-filled Wct table handles rh/rw>=5 without branches.
//
// y layout (phase-minor, d_ws): y[(n*243 + r*27 + wc*3 + ci)*64 + p],
// p = ph*8 + pw. k_conv lane=p reads are coalesced; in k_step a 64-lane wave
// is exactly one (n,r,wc,ci) over all 64 p -> a/x/lam are wave-uniform.

#define ITERS 200
#define NY 995328               // 64*243*64 y elements
#define YOFF 0
#define AOFF 995328             // a[n][oh][ow][co]: 64*243
#define WAOFF 1010880           // W_A: 14400
#define WCTOFF 1025280          // Wct: 576
#define BETAOFF 1025856         // beta table: 200   (total 1,026,056 floats ~ 4.1 MB)

template <int CTRL>
__device__ __forceinline__ float dpp_add(float x) {
  int moved = __builtin_amdgcn_update_dpp(0, __float_as_int(x), CTRL, 0xF, 0xF, true);
  return x + __int_as_float(moved);
}
// gfx9 wave64 sum; result valid in lane 63. Proven in R2/R4/R5.
__device__ __forceinline__ float wave_sum64_to_lane63(float x) {
  x = dpp_add<0x111>(x);
  x = dpp_add<0x112>(x);
  x = dpp_add<0x114>(x);
  x = dpp_add<0x118>(x);
  x = dpp_add<0x142>(x);
  x = dpp_add<0x143>(x);
  return x;
}

// One-time init (re-runs every call; d_ws is re-poisoned each timed call):
// zero y, reorder weights (R2-proven index math), build beta table.
// W_A[((th*5+tw)*3+ci)*192 + p*3 + co] = w_conv[8*th+ph][8*tw+pw][ci][co]
// Wct[((rh*8+rw)*3+c)*3 + ci] = (rh<5 && rw<5) ? w_ct[4-rh][4-rw][ci][c] : 0
__global__ void k0_init(const float* __restrict__ w_conv,
                        const float* __restrict__ w_ct,
                        float* __restrict__ ws) {
  const int i = blockIdx.x * 256 + threadIdx.x;
  if (i < NY) ws[YOFF + i] = 0.f;
  if (i < 14400) {
    int co = i % 3;
    int rest = i / 3;
    int p = rest % 64;
    int j = rest / 64;
    int ci = j % 3;
    int tt = j / 3;
    int tw = tt % 5;
    int th = tt / 5;
    int pw = p % 8;
    int ph = p / 8;
    ws[WAOFF + i] = w_conv[(((8 * th + ph) * 40 + (8 * tw + pw)) * 3 + ci) * 3 + co];
  }
  if (i < 576) {
    int ci = i % 3;
    int r1 = i / 3;
    int c = r1 % 3;
    int r2 = r1 / 3;
    int rw = r2 % 8;
    int rh = r2 / 8;
    float v = 0.f;
    if (rh < 5 && rw < 5) v = w_ct[(((4 - rh) * 5 + (4 - rw)) * 3 + ci) * 3 + c];
    ws[WCTOFF + i] = v;
  }
  if (i == 0) {
    float t = 1.0f;
#pragma unroll 1
    for (int k = 0; k < ITERS; ++k) {
      const float tn = (1.0f + sqrtf(1.0f + 4.0f * t * t)) * 0.5f;
      ws[BETAOFF + k] = (t - 1.0f) / tn;  // beta_0 = 0
      t = tn;
    }
  }
}

// a[n][oh][ow][co] = b_conv[co] + sum_{p,th,tw,ci} y[p][oh+th-2][ow+tw-2][ci]
//                    * W_A[p][th][tw][ci][co]
// block = (co, 3x3 tile (bh,bw), n); lane = phase p. Straight-line tap loops,
// no window rotation, no lambda. Live regs ~ w25 + yrow7 + acc9 + temps < 64.
__global__ __launch_bounds__(64) void k_conv(
    const float* __restrict__ Y, const float* __restrict__ WA,
    const float* __restrict__ b_conv, float* __restrict__ A) {
  const int bx = blockIdx.x;       // 0..26
  const int co = bx % 3;
  const int job = bx / 3;          // 0..8
  const int bh = job / 3;
  const int bw = job - bh * 3;
  const int n = blockIdx.y;
  const int p = threadIdx.x;       // lane = phase

  float acc[9];
#pragma unroll
  for (int k = 0; k < 9; ++k) acc[k] = 0.f;

#pragma unroll 1
  for (int ci = 0; ci < 3; ++ci) {
    float w[25];
#pragma unroll
    for (int t = 0; t < 25; ++t) w[t] = WA[(t * 3 + ci) * 192 + p * 3 + co];

#pragma unroll
    for (int r7 = 0; r7 < 7; ++r7) {
      const int r = 3 * bh - 2 + r7;           // input row on the 9x9 grid
      if (r >= 0 && r <= 8) {
        float yrow[7];
#pragma unroll
        for (int k = 0; k < 7; ++k) {
          const int wc = 3 * bw - 2 + k;       // input col
          yrow[k] = (wc >= 0 && wc <= 8)
                        ? Y[(n * 243 + r * 27 + wc * 3 + ci) * 64 + p]
                        : 0.f;
        }
#pragma unroll
        for (int pr = 0; pr < 3; ++pr) {
          const int th = r7 - pr;              // r = 3bh + pr + th - 2
          if (th >= 0 && th <= 4) {
#pragma unroll
            for (int tw = 0; tw < 5; ++tw) {
              const float wv = w[th * 5 + tw];
#pragma unroll
              for (int pc = 0; pc < 3; ++pc)
                acc[pr * 3 + pc] += yrow[pc + tw] * wv;
            }
          }
        }
      }
    }
  }

#pragma unroll
  for (int k = 0; k < 9; ++k) acc[k] = wave_sum64_to_lane63(acc[k]);
  if (p == 63) {
    const float bc = b_conv[co];
#pragma unroll
    for (int k = 0; k < 9; ++k) {
      const int oh = 3 * bh + k / 3;
      const int ow = 3 * bw + k % 3;
      A[n * 243 + oh * 27 + ow * 3 + co] = acc[k] + bc;
    }
  }
}

// One thread per y element. idx = (n*243 + qh*27 + qw*3 + c)*64 + p,
// p = part*8 + rw. Wave-uniform a/x/lam; coalesced y/ylast.
__global__ __launch_bounds__(256) void k_step(
    float* __restrict__ Y, const float* __restrict__ A,
    const float* __restrict__ x, const float* __restrict__ lam,
    const float* __restrict__ b_ct, const float* __restrict__ WCT,
    const float* __restrict__ BETA, float* __restrict__ out, int iter) {
  const int idx = blockIdx.x * 256 + threadIdx.x;  // grid exact: 3888*256 = NY
  const int p = idx & 63;
  const int q = idx >> 6;          // wave-uniform
  const int n = q / 243;
  const int pix = q - n * 243;     // qh*27 + qw*3 + c
  const int qh = pix / 27;
  const int r2 = pix - qh * 27;
  const int qw = r2 / 3;
  const int c = r2 - qw * 3;
  const int part = p >> 3;         // row phase rh
  const int rw = p & 7;            // col phase

  const float a0 = A[n * 243 + qh * 27 + qw * 3 + 0];
  const float a1 = A[n * 243 + qh * 27 + qw * 3 + 1];
  const float a2 = A[n * 243 + qh * 27 + qw * 3 + 2];
  const float r0 = x[(n * 81 + qh * 9 + qw) * 3 + 0] - a0;
  const float r1 = x[(n * 81 + qh * 9 + qw) * 3 + 1] - a1;
  const float r2v = x[(n * 81 + qh * 9 + qw) * 3 + 2] - a2;

  const float* wp = WCT + (p * 3 + c) * 3;   // ((part*8+rw)*3+c)*3, p = part*8+rw
  const float re = b_ct[c] + r0 * wp[0] + r1 * wp[1] + r2v * wp[2];

  const float yt = Y[idx];
  const float wv = yt - re;
  const float lam_n = lam[n];
  const float yn = fmaxf(wv - lam_n, 0.f) - fmaxf(-wv - lam_n, 0.f);

  if (iter < ITERS - 1) {
    const float beta = BETA[iter];           // beta_0 = 0: poison-safe ylast
    const float yl = out[idx];               // ylast scratch in d_out
    out[idx] = yn;
    Y[idx] = yn + beta * (yn - yl);
  } else {
    // final iteration: y_new IS the output; bijection idx <-> NHWC position.
    const int ih = 8 * qh + part;
    const int iw = 8 * qw + rw;
    out[((n * 72 + ih) * 72 + iw) * 3 + c] = yn;
  }
}

extern "C" void kernel_launch(void* const* d_in, const int* in_sizes, int n_in,
                              void* d_out, int out_size, void* d_ws, size_t ws_size,
                              hipStream_t stream) {
  const float* x      = (const float*)d_in[0];
  const float* lam    = (const float*)d_in[1];
  const float* w_conv = (const float*)d_in[2];
  const float* b_conv = (const float*)d_in[3];
  const float* w_ct   = (const float*)d_in[4];
  const float* b_ct   = (const float*)d_in[5];
  float* out = (float*)d_out;
  float* ws  = (float*)d_ws;  // needs ~4.11 MB

  float* Y    = ws + YOFF;
  float* A    = ws + AOFF;
  float* WA   = ws + WAOFF;
  float* WCT  = ws + WCTOFF;
  float* BETA = ws + BETAOFF;

  hipLaunchKernelGGL(k0_init, dim3(3888), dim3(256), 0, stream, w_conv, w_ct, ws);

  for (int it = 0; it < ITERS; ++it) {
    hipLaunchKernelGGL(k_conv, dim3(27, 64), dim3(64), 0, stream, Y, WA, b_conv, A);
    hipLaunchKernelGGL(k_step, dim3(3888), dim3(256), 0, stream,
                       Y, A, x, lam, b_ct, WCT, BETA, out, it);
  }
}